// Round 1
// baseline (103.833 us; speedup 1.0000x reference)
//
#include <hip/hip_runtime.h>

#define NB 256   // num_basis
#define NO 32    // output_size
#define NI 128   // input_size
// pairs = NB*NO = 8192

__global__ __launch_bounds__(256) void rbf_quad_kernel(
    const float* __restrict__ x,        // [NI]
    const float* __restrict__ centers,  // [NB][NO][NI]
    const float* __restrict__ Lam,      // [NB][NO][NI][NI]
    float* __restrict__ rbf)            // [NB*NO]
{
    __shared__ float diff_lds[4][NI];
    const int lane = threadIdx.x & 63;
    const int wid  = threadIdx.x >> 6;
    const int p    = blockIdx.x * 4 + wid;   // pair index = b*NO + o

    // diff = x - centers[p], 2 elements per lane
    const float2 xv = *(const float2*)(x + 2 * lane);
    const float2 cv = *(const float2*)(centers + (size_t)p * NI + 2 * lane);
    const float d0 = xv.x - cv.x;
    const float d1 = xv.y - cv.y;
    *(float2*)(&diff_lds[wid][2 * lane]) = make_float2(d0, d1);
    __syncthreads();

    // quad = sum_i diff[i] * (sum_j Lam[p][i][j] * diff[j])
    // lane handles columns j = 2*lane, 2*lane+1 for every row i.
    const float2* __restrict__ Lrow =
        (const float2*)(Lam + (size_t)p * (NI * NI));
    float acc = 0.0f;
    #pragma unroll 8
    for (int i = 0; i < NI; ++i) {
        const float  di = diff_lds[wid][i];      // broadcast read
        const float2 L  = Lrow[(size_t)i * 64 + lane];
        acc = fmaf(di, fmaf(L.x, d0, L.y * d1), acc);
    }

    // wave64 reduction
    #pragma unroll
    for (int off = 32; off; off >>= 1) acc += __shfl_xor(acc, off);

    if (lane == 0) rbf[p] = expf(-0.5f * acc);
}

__global__ __launch_bounds__(256) void rbf_policy_kernel(
    const float* __restrict__ weights,  // [NO][NB]
    const float* __restrict__ rbf,      // [NB][NO]  (indexed [b*NO + o])
    const float* __restrict__ bnds,     // [2][NO]
    float* __restrict__ out)            // [NO]
{
    const int o = blockIdx.x;
    const int t = threadIdx.x;          // t == b

    float v = weights[o * NB + t] * rbf[t * NO + o];

    #pragma unroll
    for (int off = 32; off; off >>= 1) v += __shfl_xor(v, off);

    __shared__ float part[4];
    if ((t & 63) == 0) part[t >> 6] = v;
    __syncthreads();

    if (t == 0) {
        const float s   = part[0] + part[1] + part[2] + part[3];
        const float pol = tanhf(s);
        const float lo  = bnds[o];
        const float hi  = bnds[NO + o];
        out[o] = (pol + 1.0f) * 0.5f * (hi - lo) + lo;
    }
}

extern "C" void kernel_launch(void* const* d_in, const int* in_sizes, int n_in,
                              void* d_out, int out_size, void* d_ws, size_t ws_size,
                              hipStream_t stream) {
    const float* x       = (const float*)d_in[0];
    const float* weights = (const float*)d_in[1];
    const float* centers = (const float*)d_in[2];
    const float* Lam     = (const float*)d_in[3];
    const float* bnds    = (const float*)d_in[4];
    float* out = (float*)d_out;
    float* rbf = (float*)d_ws;   // NB*NO floats = 32 KB

    // 8192 pairs, 1 wave each, 4 waves/block -> 2048 blocks
    rbf_quad_kernel<<<2048, 256, 0, stream>>>(x, centers, Lam, rbf);
    rbf_policy_kernel<<<NO, NB, 0, stream>>>(weights, rbf, bnds, out);
}

// Round 2
// 101.937 us; speedup vs baseline: 1.0186x; 1.0186x over previous
//
#include <hip/hip_runtime.h>

#define NB 256   // num_basis
#define NO 32    // output_size
#define NI 128   // input_size
// pairs = NB*NO = 8192

__global__ __launch_bounds__(256, 8) void rbf_quad_kernel(
    const float* __restrict__ x,        // [NI]
    const float* __restrict__ centers,  // [NB][NO][NI]
    const float* __restrict__ Lam,      // [NB][NO][NI][NI]
    float* __restrict__ rbf)            // [NB*NO]
{
    __shared__ float diff_lds[4][NI];
    const int lane = threadIdx.x & 63;
    const int wid  = threadIdx.x >> 6;
    const int p    = blockIdx.x * 4 + wid;   // pair index = b*NO + o

    // diff = x - centers[p], 2 elements per lane -> LDS
    const float2 xv = *(const float2*)(x + 2 * lane);
    const float2 cv = *(const float2*)(centers + (size_t)p * NI + 2 * lane);
    *(float2*)(&diff_lds[wid][2 * lane]) = make_float2(xv.x - cv.x, xv.y - cv.y);
    __syncthreads();

    // Each lane owns 4 columns c..c+3; half-wave h covers row 2*it+h.
    const int c = 4 * (lane & 31);
    const int h = lane >> 5;
    const float4 dj = *(const float4*)(&diff_lds[wid][c]);

    // One float4 load per lane per iteration = 1 KiB/wave = rows 2it, 2it+1.
    const float4* __restrict__ Lrow = (const float4*)(Lam + (size_t)p * (NI * NI));
    float acc = 0.0f;
    #pragma unroll 8
    for (int it = 0; it < NI / 2; ++it) {
        const float4 L  = Lrow[(size_t)it * 64 + lane];
        const float  di = diff_lds[wid][2 * it + h];   // dual broadcast, conflict-free
        acc = fmaf(di,
                   fmaf(L.x, dj.x, fmaf(L.y, dj.y, fmaf(L.z, dj.z, L.w * dj.w))),
                   acc);
    }

    // wave64 reduction (covers both halves -> all rows, all columns)
    #pragma unroll
    for (int off = 32; off; off >>= 1) acc += __shfl_xor(acc, off);

    if (lane == 0) rbf[p] = expf(-0.5f * acc);
}

__global__ __launch_bounds__(256) void rbf_policy_kernel(
    const float* __restrict__ weights,  // [NO][NB]
    const float* __restrict__ rbf,      // [NB][NO]  (indexed [b*NO + o])
    const float* __restrict__ bnds,     // [2][NO]
    float* __restrict__ out)            // [NO]
{
    const int o = blockIdx.x;
    const int t = threadIdx.x;          // t == b

    float v = weights[o * NB + t] * rbf[t * NO + o];

    #pragma unroll
    for (int off = 32; off; off >>= 1) v += __shfl_xor(v, off);

    __shared__ float part[4];
    if ((t & 63) == 0) part[t >> 6] = v;
    __syncthreads();

    if (t == 0) {
        const float s   = part[0] + part[1] + part[2] + part[3];
        const float pol = tanhf(s);
        const float lo  = bnds[o];
        const float hi  = bnds[NO + o];
        out[o] = (pol + 1.0f) * 0.5f * (hi - lo) + lo;
    }
}

extern "C" void kernel_launch(void* const* d_in, const int* in_sizes, int n_in,
                              void* d_out, int out_size, void* d_ws, size_t ws_size,
                              hipStream_t stream) {
    const float* x       = (const float*)d_in[0];
    const float* weights = (const float*)d_in[1];
    const float* centers = (const float*)d_in[2];
    const float* Lam     = (const float*)d_in[3];
    const float* bnds    = (const float*)d_in[4];
    float* out = (float*)d_out;
    float* rbf = (float*)d_ws;   // NB*NO floats = 32 KB

    // 8192 pairs, 1 wave each, 4 waves/block -> 2048 blocks (8 blocks/CU)
    rbf_quad_kernel<<<2048, 256, 0, stream>>>(x, centers, Lam, rbf);
    rbf_policy_kernel<<<NO, NB, 0, stream>>>(weights, rbf, bnds, out);
}

// Round 4
// 87.213 us; speedup vs baseline: 1.1906x; 1.1688x over previous
//
#include <hip/hip_runtime.h>

#define NB 256   // num_basis
#define NO 32    // output_size
#define NI 128   // input_size
// pairs = NB*NO = 8192; Lambda_inv = 512 MB fp32

typedef float f32x4 __attribute__((ext_vector_type(4)));

__global__ __launch_bounds__(256, 4) void rbf_quad_kernel(
    const float* __restrict__ x,        // [NI]
    const float* __restrict__ centers,  // [NB][NO][NI]
    const float* __restrict__ Lam,      // [NB][NO][NI][NI]
    float* __restrict__ rbf)            // [NB*NO]
{
    __shared__ float diff_lds[4][NI];
    const int lane = threadIdx.x & 63;
    const int wid  = threadIdx.x >> 6;
    const int p    = blockIdx.x * 4 + wid;   // pair index = b*NO + o

    // diff = x - centers[p], 2 elements per lane -> LDS
    const float2 xv = *(const float2*)(x + 2 * lane);
    const float2 cv = *(const float2*)(centers + (size_t)p * NI + 2 * lane);
    *(float2*)(&diff_lds[wid][2 * lane]) = make_float2(xv.x - cv.x, xv.y - cv.y);
    __syncthreads();

    // Lane owns columns c..c+3 (held in dj); half-wave h picks the row
    // within each 2-row slab.
    const int c = 4 * (lane & 31);
    const int h = lane >> 5;
    const f32x4 dj = *(const f32x4*)(&diff_lds[wid][c]);

    const f32x4* __restrict__ Lq = (const f32x4*)(Lam + (size_t)p * (NI * NI));
    float acc0 = 0.0f, acc1 = 0.0f;

    // Per iteration: 2 KiB/wave = rows 4it..4it+3.
    //   L0 (rows 4it,4it+1)   : NORMAL load  -> LLC-allocating (256 MB set)
    //   L1 (rows 4it+2,4it+3) : NONTEMPORAL  -> streams, no LLC alloc
    // Steady state across graph replays: half the footprint L3-resident.
    #pragma unroll 8
    for (int it = 0; it < NI / 4; ++it) {
        const f32x4 L0 = Lq[(size_t)it * 128 + lane];
        const f32x4 L1 = __builtin_nontemporal_load(Lq + (size_t)it * 128 + 64 + lane);
        const float di0 = diff_lds[wid][4 * it + h];
        const float di1 = diff_lds[wid][4 * it + 2 + h];
        acc0 = fmaf(di0,
                    fmaf(L0.x, dj.x, fmaf(L0.y, dj.y, fmaf(L0.z, dj.z, L0.w * dj.w))),
                    acc0);
        acc1 = fmaf(di1,
                    fmaf(L1.x, dj.x, fmaf(L1.y, dj.y, fmaf(L1.z, dj.z, L1.w * dj.w))),
                    acc1);
    }

    float acc = acc0 + acc1;
    #pragma unroll
    for (int off = 32; off; off >>= 1) acc += __shfl_xor(acc, off);

    if (lane == 0) rbf[p] = expf(-0.5f * acc);
}

__global__ __launch_bounds__(256) void rbf_policy_kernel(
    const float* __restrict__ weights,  // [NO][NB]
    const float* __restrict__ rbf,      // [NB][NO]  (indexed [b*NO + o])
    const float* __restrict__ bnds,     // [2][NO]
    float* __restrict__ out)            // [NO]
{
    const int o = blockIdx.x;
    const int t = threadIdx.x;          // t == b

    float v = weights[o * NB + t] * rbf[t * NO + o];

    #pragma unroll
    for (int off = 32; off; off >>= 1) v += __shfl_xor(v, off);

    __shared__ float part[4];
    if ((t & 63) == 0) part[t >> 6] = v;
    __syncthreads();

    if (t == 0) {
        const float s   = part[0] + part[1] + part[2] + part[3];
        const float pol = tanhf(s);
        const float lo  = bnds[o];
        const float hi  = bnds[NO + o];
        out[o] = (pol + 1.0f) * 0.5f * (hi - lo) + lo;
    }
}

extern "C" void kernel_launch(void* const* d_in, const int* in_sizes, int n_in,
                              void* d_out, int out_size, void* d_ws, size_t ws_size,
                              hipStream_t stream) {
    const float* x       = (const float*)d_in[0];
    const float* weights = (const float*)d_in[1];
    const float* centers = (const float*)d_in[2];
    const float* Lam     = (const float*)d_in[3];
    const float* bnds    = (const float*)d_in[4];
    float* out = (float*)d_out;
    float* rbf = (float*)d_ws;   // NB*NO floats = 32 KB

    rbf_quad_kernel<<<2048, 256, 0, stream>>>(x, centers, Lam, rbf);
    rbf_policy_kernel<<<NO, NB, 0, stream>>>(weights, rbf, bnds, out);
}